// Round 1
// 305.918 us; speedup vs baseline: 1.0310x; 1.0310x over previous
//
#include <hip/hip_runtime.h>
#include <math.h>

// Sizes (fixed for this problem)
#define B 2
#define T 2048
#define H 1024
#define NH 16
#define HD 64
#define FF 4096
#define M_TOK (B*T)          // 4096 token rows
#define LOG2E 1.4426950408889634f

typedef unsigned short u16;
typedef __attribute__((ext_vector_type(8))) short bf16x8;
typedef __attribute__((ext_vector_type(4))) float f32x4;

// counted-vmcnt barrier: wait until only N of this wave's vmem ops remain,
// then workgroup barrier. Single asm with "memory" clobber so no memory op
// (gload_lds / ds_read) is reordered across it.
// NOTE (r8-r10 lesson): counted-vmcnt pipelines are only safe when EVERY
// LDS buffer is >=3 slots deep (overwrite target >=2 iterations stale).
#define WAITBAR3  asm volatile("s_waitcnt vmcnt(3)\n\ts_barrier" ::: "memory")
#define WAITBAR4  asm volatile("s_waitcnt vmcnt(4)\n\ts_barrier" ::: "memory")
#define WAITBAR0  asm volatile("s_waitcnt vmcnt(0)\n\ts_barrier" ::: "memory")

__device__ __forceinline__ u16 f2bf(float f) {
  union { float f; unsigned u; } v; v.f = f;
  const unsigned r = (v.u + 0x7FFFu + ((v.u >> 16) & 1u)) >> 16;
  return (u16)r;
}
__device__ __forceinline__ float bf2f(u16 h) {
  union { unsigned u; float f; } v; v.u = ((unsigned)h) << 16;
  return v.f;
}
__device__ __forceinline__ unsigned cvt_pk_bf16(float lo, float hi) {
  unsigned r;
  asm("v_cvt_pk_bf16_f32 %0, %1, %2" : "=v"(r) : "v"(lo), "v"(hi));
  return r;
}
__device__ __forceinline__ float m3(float a, float b, float c) {
  return fmaxf(fmaxf(a, b), c);      // clang fuses to v_max3_f32
}
// async global->LDS, 16B per lane; dest = wave-uniform base + lane*16
__device__ __forceinline__ void gload16(const u16* g, u16* l) {
  __builtin_amdgcn_global_load_lds(
      (const __attribute__((address_space(1))) unsigned int*)g,
      (__attribute__((address_space(3))) unsigned int*)l, 16, 0, 0);
}

// ---------------------------------------------------------------------------
// split fp32 -> bf16 hi + bf16 lo (Dekker split; hi+lo ~ fp32 accurate)
// ---------------------------------------------------------------------------
__global__ __launch_bounds__(256) void split_hl(
    const float* __restrict__ in, u16* __restrict__ oh, u16* __restrict__ ol)
{
  const size_t i = ((size_t)blockIdx.x * 256 + threadIdx.x) * 4;
  const float4 v = *(const float4*)(in + i);
  union { u16 s[4]; uint2 u; } h, l;
  const float f[4] = {v.x, v.y, v.z, v.w};
#pragma unroll
  for (int j = 0; j < 4; ++j) {
    const u16 hb = f2bf(f[j]); h.s[j] = hb; l.s[j] = f2bf(f[j] - bf2f(hb));
  }
  *(uint2*)(oh + i) = h.u;
  *(uint2*)(ol + i) = l.u;
}

// ---------------------------------------------------------------------------
// transpose-convert: in [K][N] fp32 -> out [N][K] bf16 (hi, + lo if SPLIT)
// ---------------------------------------------------------------------------
template<int SPLIT>
__global__ __launch_bounds__(256) void transpose_bf16(
    const float* __restrict__ in, u16* __restrict__ oh, u16* __restrict__ ol,
    int K, int N)
{
  __shared__ float tile[64][69];
  const int k0 = blockIdx.y * 64, n0 = blockIdx.x * 64;
  const int tid = threadIdx.x;
  const int r = tid >> 4, c4 = (tid & 15) * 4;
#pragma unroll
  for (int i = 0; i < 4; ++i) {
    const float4 v = *(const float4*)(in + (size_t)(k0 + i*16 + r) * N + n0 + c4);
    tile[i*16+r][c4]   = v.x; tile[i*16+r][c4+1] = v.y;
    tile[i*16+r][c4+2] = v.z; tile[i*16+r][c4+3] = v.w;
  }
  __syncthreads();
  const int n = tid >> 2, kq = tid & 3;
  union { u16 s[8]; int4 v; } ph0, ph1, pl0, pl1;
#pragma unroll
  for (int j = 0; j < 8; ++j) {
    const float f0 = tile[kq*16 + j][n];
    const float f1 = tile[kq*16 + 8 + j][n];
    const u16 h0 = f2bf(f0), h1 = f2bf(f1);
    ph0.s[j] = h0; ph1.s[j] = h1;
    if (SPLIT) { pl0.s[j] = f2bf(f0 - bf2f(h0)); pl1.s[j] = f2bf(f1 - bf2f(h1)); }
  }
  u16* po = oh + (size_t)(n0 + n) * K + k0 + kq * 16;
  *(int4*)po = ph0.v; *(int4*)(po + 8) = ph1.v;
  if (SPLIT) {
    u16* pl = ol + (size_t)(n0 + n) * K + k0 + kq * 16;
    *(int4*)pl = pl0.v; *(int4*)(pl + 8) = pl1.v;
  }
}

// ---------------------------------------------------------------------------
// MFMA GEMM: C[M,N] = (A @ B^T) * bias[N]  (A [M][K] bf16, B [N][K] bf16)
// 128x128 tile, BK=32, global_load_lds staging, XCD-chunked 1-D grid.
// DEEP3 (non-split only): 3-slot LDS + counted vmcnt(4) barriers. 24KB.
// SPLIT: 2-phase double-buffered (__syncthreads drains vmcnt -> safe).
// PARTIAL: split-K=2 over blockIdx.y; raw fp32 partials (no bias/relu).
// QKV3: V fragments (qkv k-index 2) skip the hi/lo correction MFMAs, and
//       their Bl staging chunks are skipped entirely (never read).
// ---------------------------------------------------------------------------
__device__ __forceinline__ int swz(int r, int kq) {
  return r * 32 + ((kq ^ ((r >> 1) & 3)) * 8);
}

template<int SPLIT, int RELU, int OBF, int QKV3, int DEEP3, int PARTIAL>
__global__ __launch_bounds__(256) void mfma_gemm(
    const u16* __restrict__ Ah, const u16* __restrict__ Al,
    const u16* __restrict__ Bh, const u16* __restrict__ Bl,
    const float* __restrict__ bias,
    float* __restrict__ Cf, u16* __restrict__ Cb,
    int M, int N, int K)
{
  __shared__ u16 lds[DEEP3 ? 24576 : (SPLIT ? 32768 : 16384)];
  const int BUFSZ = SPLIT ? 16384 : 8192;
  const int tid = threadIdx.x;
  // XCD-chunked decode: xcd=bid&7 owns M-panels [4*xcd, 4*xcd+4)
  const int bid = blockIdx.x;
  const int xcd = bid & 7;
  const int idx = bid >> 3;
  const int row0 = (xcd * 4 + (idx & 3)) * 128;
  const int col0 = (idx >> 2) * 128;
  const int wv = tid >> 6, lane = tid & 63;
  const int wr = wv >> 1, wc = wv & 1;
  const int kq = lane >> 4, fr = lane & 15;

  int kb = 0, kE = K;
  if (PARTIAL) {
    const int khf = blockIdx.y;
    kb = khf * (K >> 1); kE = kb + (K >> 1);
    Cf += (size_t)khf * ((size_t)M * N);
  }

  f32x4 acc[4][4] = {};

  // stage one 128x32 bf16 array (8 chunks of 1KB); wave wv does chunks 2wv,2wv+1
#define GSTAGE(lbase, gb, rowbase, kk) do { \
    _Pragma("unroll") \
    for (int t_ = 0; t_ < 2; ++t_) { \
      const int c_ = wv * 2 + t_; \
      const int idx_ = c_ * 64 + lane; \
      const int r_ = idx_ >> 2; \
      const int kq_ = (idx_ & 3) ^ ((r_ >> 1) & 3); \
      gload16((gb) + (size_t)((rowbase) + r_) * K + (kk) + kq_ * 8, \
              &lds[(lbase) + c_ * 512]); \
    } } while (0)

  // Bl staging with V-group chunk skip (chunk c covers 16-col group
  // (col0>>4)+c; k-index %3==2 groups never read their b_l fragments).
#define BLSTAGE(lbase, kk) do { \
    _Pragma("unroll") \
    for (int t_ = 0; t_ < 2; ++t_) { \
      const int c_ = wv * 2 + t_; \
      if (!QKV3 || ((((col0 >> 4) + c_) % 3) != 2)) { \
        const int idx_ = c_ * 64 + lane; \
        const int r_ = idx_ >> 2; \
        const int kq_ = (idx_ & 3) ^ ((r_ >> 1) & 3); \
        gload16(Bl + (size_t)(col0 + r_) * K + (kk) + kq_ * 8, \
                &lds[(lbase) + c_ * 512]); \
      } } } while (0)

  if (DEEP3) {
    // ---- 3-deep counted-vmcnt pipeline (non-split only; all slots 3-deep,
    // overwrite target is 2 iterations stale -> no write-after-read hazard) ----
    const int nk = (kE - kb) >> 5;
    GSTAGE(0, Ah, row0, kb);            GSTAGE(4096, Bh, col0, kb);
    GSTAGE(8192, Ah, row0, kb + 32);    GSTAGE(8192 + 4096, Bh, col0, kb + 32);
    WAITBAR4;                            // stage 0 ready; stage 1 in flight
    int cslot = 0, islot = 2;
    for (int i = 0; i < nk; ++i) {
      if (i + 2 < nk) {
        const int kk = kb + (i + 2) * 32;
        GSTAGE(islot * 8192, Ah, row0, kk);
        GSTAGE(islot * 8192 + 4096, Bh, col0, kk);
        islot = (islot == 2) ? 0 : islot + 1;
      }
      const int rb = cslot * 8192;
      bf16x8 a_h[4];
#pragma unroll
      for (int m = 0; m < 4; ++m)
        a_h[m] = *(const bf16x8*)&lds[rb + swz(wr*64 + m*16 + fr, kq)];
#pragma unroll
      for (int n = 0; n < 4; ++n) {
        const bf16x8 b_h = *(const bf16x8*)&lds[rb + 4096 + swz(wc*64 + n*16 + fr, kq)];
#pragma unroll
        for (int m = 0; m < 4; ++m)
          acc[m][n] = __builtin_amdgcn_mfma_f32_16x16x32_bf16(a_h[m], b_h, acc[m][n], 0, 0, 0);
      }
      cslot = (cslot == 2) ? 0 : cslot + 1;
      if (i + 1 < nk) { if (i + 2 < nk) WAITBAR4; else WAITBAR0; }
    }
  } else {
    // ---- 2-phase double-buffered (__syncthreads drains all counters) ----
    GSTAGE(0, Ah, row0, kb);
    GSTAGE(4096, Bh, col0, kb);
    if (SPLIT) { GSTAGE(8192, Al, row0, kb); BLSTAGE(12288, kb); }
    __syncthreads();

    int cur = 0;
    for (int k0 = kb; k0 < kE; k0 += 32) {
      const int nxt = cur ^ 1;
      if (k0 + 32 < kE) {
        GSTAGE(nxt*BUFSZ, Ah, row0, k0 + 32);
        GSTAGE(nxt*BUFSZ + 4096, Bh, col0, k0 + 32);
        if (SPLIT) { GSTAGE(nxt*BUFSZ + 8192, Al, row0, k0 + 32);
                     BLSTAGE(nxt*BUFSZ + 12288, k0 + 32); }
      }
      const int rb = cur * BUFSZ;
      bf16x8 a_h[4], a_l[4];
#pragma unroll
      for (int m = 0; m < 4; ++m) {
        a_h[m] = *(const bf16x8*)&lds[rb + swz(wr*64 + m*16 + fr, kq)];
        if (SPLIT) a_l[m] = *(const bf16x8*)&lds[rb + 8192 + swz(wr*64 + m*16 + fr, kq)];
      }
#pragma unroll
      for (int n = 0; n < 4; ++n) {
        const bf16x8 b_h = *(const bf16x8*)&lds[rb + 4096 + swz(wc*64 + n*16 + fr, kq)];
#pragma unroll
        for (int m = 0; m < 4; ++m)
          acc[m][n] = __builtin_amdgcn_mfma_f32_16x16x32_bf16(a_h[m], b_h, acc[m][n], 0, 0, 0);
        if (SPLIT) {
          const bool dolo = !QKV3 || ((((col0 >> 4) + wc * 4 + n) % 3) != 2);
          if (dolo) {
            const bf16x8 b_l = *(const bf16x8*)&lds[rb + 12288 + swz(wc*64 + n*16 + fr, kq)];
#pragma unroll
            for (int m = 0; m < 4; ++m) {
              acc[m][n] = __builtin_amdgcn_mfma_f32_16x16x32_bf16(a_h[m], b_l, acc[m][n], 0, 0, 0);
              acc[m][n] = __builtin_amdgcn_mfma_f32_16x16x32_bf16(a_l[m], b_h, acc[m][n], 0, 0, 0);
            }
          }
        }
      }
      __syncthreads();
      cur = nxt;
    }
  }
#undef GSTAGE
#undef BLSTAGE

  const int orow0 = row0 + wr * 64, ocol0 = col0 + wc * 64;
#pragma unroll
  for (int n = 0; n < 4; ++n) {
    const int col = ocol0 + n * 16 + fr;
    const float bs = PARTIAL ? 1.0f : bias[col];
#pragma unroll
    for (int m = 0; m < 4; ++m) {
      const int rbase = orow0 + m * 16 + (lane >> 4) * 4;
#pragma unroll
      for (int j = 0; j < 4; ++j) {
        float v = acc[m][n][j] * bs;
        if (RELU) v = fmaxf(v, 0.0f);
        const size_t off = (size_t)(rbase + j) * N + col;
        if (OBF) Cb[off] = f2bf(v); else Cf[off] = v;
      }
    }
  }
}

// ---------------------------------------------------------------------------
// Repack qkv [B,T,3072] -> bf16 arrays: Qh/Ql (scaled by log2e/32, split),
// Kh/Kl (split), Vb (bf16), all [B*NH][T][HD]. Channel o = d*48 + k*16 + h.
// ---------------------------------------------------------------------------
__global__ __launch_bounds__(256) void repack_qkv(
    const float* __restrict__ qkv,
    u16* __restrict__ Qh, u16* __restrict__ Ql,
    u16* __restrict__ Kh, u16* __restrict__ Kl, u16* __restrict__ Vb)
{
  const int bt = blockIdx.x;
  const int b = bt >> 11, t = bt & (T - 1);
  const int tid = threadIdx.x;
  __shared__ float Ls[3 * H];
  const float* src = qkv + (size_t)bt * (3 * H);
#pragma unroll
  for (int i = 0; i < 3; ++i) {
    const int c4 = i * 256 + tid;
    *(float4*)&Ls[c4 * 4] = *(const float4*)(src + c4 * 4);
  }
  __syncthreads();
  const float qscale = LOG2E / 32.0f;
#pragma unroll
  for (int i = 0; i < 4; ++i) {
    const int j = i * 256 + tid;
    const int h = j >> 6, d = j & 63;
    const size_t dst = (((size_t)(b * NH + h)) * T + t) * HD + d;
    const float q = Ls[d * 48 + h] * qscale;
    const u16 qhb = f2bf(q);
    Qh[dst] = qhb; Ql[dst] = f2bf(q - bf2f(qhb));
    const float k = Ls[d * 48 + 16 + h];
    const u16 khb = f2bf(k);
    Kh[dst] = khb; Kl[dst] = f2bf(k - bf2f(khb));
    Vb[dst] = f2bf(Ls[d * 48 + 32 + h]);
  }
}

// ---------------------------------------------------------------------------
// Vb [bh][T][HD] bf16 -> VT [bh][HD][T] bf16 (64x64 tiles via LDS)
// ---------------------------------------------------------------------------
__global__ __launch_bounds__(256) void vtrans(
    const u16* __restrict__ Vb, u16* __restrict__ VT)
{
  __shared__ u16 Ls[64][72];
  const int bh = blockIdx.y, t0 = blockIdx.x * 64;
  const int tid = threadIdx.x;
  const int r = tid >> 2, c = (tid & 3) * 16;
  const size_t src = ((size_t)bh * T + t0 + r) * HD + c;
  *(int4*)&Ls[r][c]     = *(const int4*)(Vb + src);
  *(int4*)&Ls[r][c + 8] = *(const int4*)(Vb + src + 8);
  __syncthreads();
  const int d = tid >> 2, tc = (tid & 3) * 16;
  u16 buf[16];
#pragma unroll
  for (int i = 0; i < 16; ++i) buf[i] = Ls[tc + i][d];
  u16* dst = VT + ((size_t)bh * HD + d) * T + t0 + tc;
  *(int4*)dst       = *(int4*)&buf[0];
  *(int4*)(dst + 8) = *(int4*)&buf[8];
}

// ---------------------------------------------------------------------------
// sigma: LDS K-row r holds key sigma(r) so that the QK^T C-layout hands each
// lane exactly the 8-consecutive-key fragments PV's B-operand needs.
// ---------------------------------------------------------------------------
__device__ __forceinline__ int sigma_k(int r) {
  return ((r >> 5) << 5) | (((r >> 2) & 3) << 3) | (((r >> 4) & 1) << 2) | (r & 3);
}

// ---------------------------------------------------------------------------
// MFMA flash attention, swapped-operand. 8 waves x 16 q-rows (512 threads),
// KV tile 64. 3-deep counted-vmcnt staging pipeline (all slots 3-deep);
// XCD-clustered grid; defer-max (THR=8); lsum via ones-A MFMA; setprio.
// 72KB LDS x 2 blocks/CU = 144KB <= 160KB -> 16 waves/CU (4/SIMD), double
// the previous 4-wave/256-thread variant's residency. __launch_bounds__
// (512,4) forces VGPR<=128 so the 2-block residency is guaranteed.
// ---------------------------------------------------------------------------
__global__ __launch_bounds__(512, 4) void flash_attn_mfma(
    const u16* __restrict__ Qh, const u16* __restrict__ Ql,
    const u16* __restrict__ Kh, const u16* __restrict__ Kl,
    const u16* __restrict__ VT, float* __restrict__ Out)
{
  __shared__ u16 sm[3 * 12288];  // slot: KH [0,4K) | KL [4K,8K) | VT [8K,12K) u16
  // XCD-clustered decode: xcd = i&7 owns heads 4*xcd..4*xcd+3
  const int i = blockIdx.x;
  const int slot = i >> 3;
  const int bh = (i & 7) * 4 + (slot >> 4);
  const int row0 = (slot & 15) * 128;
  const int b = bh >> 4, h = bh & 15;
  const int tid = threadIdx.x, wave = tid >> 6, lane = tid & 63;
  const int fr = lane & 15, kq = lane >> 4;

  // Q fragments (B-operand: col=q=fr, k=d=kq*8 within ks*32); wave owns
  // q-rows [row0 + wave*16, +16)
  bf16x8 qh[2], ql[2];
  const size_t qoff = ((size_t)bh * T + row0 + wave*16 + fr) * HD + kq*8;
#pragma unroll
  for (int ks = 0; ks < 2; ++ks) {
    qh[ks] = *(const bf16x8*)(Qh + qoff + ks*32);
    ql[ks] = *(const bf16x8*)(Ql + qoff + ks*32);
  }

  bf16x8 ones8;
#pragma unroll
  for (int z = 0; z < 8; ++z) ones8[z] = (short)0x3F80;

  f32x4 o[4] = {};
  f32x4 oex = {};                      // lsum accumulator (all 4 rows equal)
  float m_ = -1e30f;

  // staging: wave w stages chunk w (1KB) of each of the 3 arrays (8 waves
  // cover the 8 chunks). Global pointers advance by a constant per KV tile.
  const int c_ = wave;
  const int r0_ = c_ * 8 + (lane >> 3), s_ = lane & 7;
  const int cd0 = s_ ^ (r0_ & 7);
  const int k0_ = sigma_k(r0_);
  const u16* pKh0 = Kh + ((size_t)bh*T + k0_)*HD + cd0*8;
  const u16* pKl0 = Kl + ((size_t)bh*T + k0_)*HD + cd0*8;
  const u16* pV0  = VT + ((size_t)bh*HD + r0_)*T + cd0*8;

#define FSTAGE(sb) do { \
    gload16(pKh0, &sm[(sb) + c_*512]); \
    gload16(pKl0, &sm[(sb) + 4096 + c_*512]); \
    gload16(pV0,  &sm[(sb) + 8192 + c_*512]); \
    pKh0 += 64*HD; pKl0 += 64*HD; pV0 += 64; \
  } while (0)

  FSTAGE(0);
  FSTAGE(12288);
  WAITBAR3;                  // tile 0 ready (3 loads/wave); tile 1 in flight
  int cslot = 0, islot = 2;

  const int NT = T / 64;
  for (int t = 0; t < NT; ++t) {
    if (t + 2 < NT) {
      FSTAGE(islot * 12288);
      islot = (islot == 2) ? 0 : islot + 1;
    }
    const u16* smb = &sm[cslot * 12288];

    // ---- QK^T (swapped): s[n], keys sigma(16n+4kq+jj), q=fr
    f32x4 s[4] = {};
    __builtin_amdgcn_s_setprio(1);
#pragma unroll
    for (int ks = 0; ks < 2; ++ks) {
#pragma unroll
      for (int n = 0; n < 4; ++n) {
        const int kr = n * 16 + fr;
        const int sl = ((ks*4 + kq) ^ (kr & 7)) * 8;
        const bf16x8 kh_ = *(const bf16x8*)&smb[kr*64 + sl];
        const bf16x8 kl_ = *(const bf16x8*)&smb[4096 + kr*64 + sl];
        s[n] = __builtin_amdgcn_mfma_f32_16x16x32_bf16(kh_, qh[ks], s[n], 0, 0, 0);
        s[n] = __builtin_amdgcn_mfma_f32_16x16x32_bf16(kl_, qh[ks], s[n], 0, 0, 0);
        s[n] = __builtin_amdgcn_mfma_f32_16x16x32_bf16(kh_, ql[ks], s[n], 0, 0, 0);
      }
    }
    __builtin_amdgcn_s_setprio(0);

    // ---- defer-max softmax (THR=8)
    const float g0 = m3(s[0][0], s[0][1], s[0][2]);
    const float g1 = m3(s[0][3], s[1][0], s[1][1]);
    const float g2 = m3(s[1][2], s[1][3], s[2][0]);
    const float g3 = m3(s[2][1], s[2][2], s[2][3]);
    const float g4 = m3(s[3][0], s[3][1], s[3][2]);
    float mx = fmaxf(m3(g0, g1, g2), m3(g3, g4, s[3][3]));
    mx = fmaxf(mx, __shfl_xor(mx, 16));
    mx = fmaxf(mx, __shfl_xor(mx, 32));
    if (!__all(mx <= m_ + 8.0f)) {      // record tile (~10%): rescale
      const float mn = fmaxf(m_, mx);
      const float fsc = exp2f(m_ - mn);
      m_ = mn;
#pragma unroll
      for (int n = 0; n < 4; ++n) {
        o[n][0] *= fsc; o[n][1] *= fsc;
        o[n][2] *= fsc; o[n][3] *= fsc;
      }
      oex[0] *= fsc; oex[1] *= fsc; oex[2] *= fsc; oex[3] *= fsc;
    }

    float p[4][4];
#pragma unroll
    for (int n = 0; n < 4; ++n)
#pragma unroll
      for (int jj = 0; jj < 4; ++jj)
        p[n][jj] = exp2f(s[n][jj] - m_);

    unsigned pk[4][2];
#pragma unroll
    for (int n = 0; n < 4; ++n) {
      pk[n][0] = cvt_pk_bf16(p[n][0], p[n][1]);
      pk[n][1] = cvt_pk_bf16(p[n][2], p[n][3]);
    }

    // ---- in-reg P -> PV (+ lsum MFMA); V^T fragments read inline
    __builtin_amdgcn_s_setprio(1);
#pragma unroll
    for (int ks = 0; ks < 2; ++ks) {
      union { unsigned u[4]; bf16x8 v; } pb;
      pb.u[0] = pk[2*ks][0];   pb.u[1] = pk[2*ks][1];
      pb.u[2] = pk[2*ks+1][0]; pb.u[3] = pk[2*ks+1][1];
#pragma unroll
      for (int n = 0; n < 4; ++n) {
        const int dr = n * 16 + fr;
        const bf16x8 vf = *(const bf16x8*)&smb[8192 + dr*64 + (((ks*4 + kq) ^ (dr & 7)) * 8)];
        o[n] = __builtin_amdgcn_mfma_f32_16x16x32_bf16(vf, pb.v, o[n], 0, 0, 0);
      }
      oex = __builtin_amdgcn_mfma_f32_16x16x32_bf16(ones8, pb.v, oex, 0, 0, 0);
    }
    __builtin_amdgcn_s_setprio(0);

    cslot = (cslot == 2) ? 0 : cslot + 1;
    if (t + 1 < NT) { if (t + 2 < NT) WAITBAR3; else WAITBAR0; }
  }
#undef FSTAGE

  // ---- epilogue: O^T frag has q=fr, d = 16n + 4kq + jj (jj contiguous)
  {
    const float inv = 1.0f / oex[0];
    const size_t qrow = (size_t)b * T + row0 + wave*16 + fr;
#pragma unroll
    for (int n = 0; n < 4; ++n) {
      float4 ov;
      ov.x = o[n][0] * inv; ov.y = o[n][1] * inv;
      ov.z = o[n][2] * inv; ov.w = o[n][3] * inv;
      *(float4*)(Out + qrow * H + h * HD + n * 16 + kq * 4) = ov;
    }
  }
}

// ---------------------------------------------------------------------------
// out = LN(a + b) * gamma + beta; ddof=1, eps on std. Optional bf16 copy.
// ---------------------------------------------------------------------------
__global__ __launch_bounds__(256) void ln_residual(
    const float* __restrict__ A, const float* __restrict__ Bz,
    const float* __restrict__ gamma, const float* __restrict__ beta,
    float* __restrict__ out, u16* __restrict__ obf)
{
  const int row = blockIdx.x, tid = threadIdx.x;
  const int wave = tid >> 6, lane = tid & 63;
  const size_t off = (size_t)row * H + tid * 4;
  const float4 av = *(const float4*)(A + off);
  const float4 bv = *(const float4*)(Bz + off);
  float4 y; y.x = av.x + bv.x; y.y = av.y + bv.y; y.z = av.z + bv.z; y.w = av.w + bv.w;
  float s  = y.x + y.y + y.z + y.w;
  float ss = y.x*y.x + y.y*y.y + y.z*y.z + y.w*y.w;
#pragma unroll
  for (int o = 32; o >= 1; o >>= 1) { s += __shfl_xor(s, o); ss += __shfl_xor(ss, o); }
  __shared__ float red[2][4];
  if (lane == 0) { red[0][wave] = s; red[1][wave] = ss; }
  __syncthreads();
  s  = red[0][0] + red[0][1] + red[0][2] + red[0][3];
  ss = red[1][0] + red[1][1] + red[1][2] + red[1][3];
  const float mean = s * (1.0f / (float)H);
  float var = (ss - (float)H * mean * mean) * (1.0f / (float)(H - 1));
  var = fmaxf(var, 0.0f);
  const float inv = 1.0f / (sqrtf(var) + 1e-6f);
  const float4 gv = *(const float4*)(gamma + tid * 4);
  const float4 be = *(const float4*)(beta + tid * 4);
  float4 o;
  o.x = gv.x * (y.x - mean) * inv + be.x;
  o.y = gv.y * (y.y - mean) * inv + be.y;
  o.z = gv.z * (y.z - mean) * inv + be.z;
  o.w = gv.w * (y.w - mean) * inv + be.w;
  *(float4*)(out + off) = o;
  if (obf) {
    union { u16 s[4]; uint2 u; } pk;
    pk.s[0] = f2bf(o.x); pk.s[1] = f2bf(o.y); pk.s[2] = f2bf(o.z); pk.s[3] = f2bf(o.w);
    *(uint2*)(obf + off) = pk.u;
  }
}

// ---------------------------------------------------------------------------
// split-K merge + LN: out = LN(a + (pA+pB)*bb) * gamma + beta
// ---------------------------------------------------------------------------
__global__ __launch_bounds__(256) void ln_residual_sk(
    const float* __restrict__ A, const float* __restrict__ PA,
    const float* __restrict__ PB, const float* __restrict__ bb,
    const float* __restrict__ gamma, const float* __restrict__ beta,
    float* __restrict__ out)
{
  const int row = blockIdx.x, tid = threadIdx.x;
  const int wave = tid >> 6, lane = tid & 63;
  const size_t off = (size_t)row * H + tid * 4;
  const float4 av = *(const float4*)(A + off);
  const float4 pa = *(const float4*)(PA + off);
  const float4 pb = *(const float4*)(PB + off);
  const float4 bw = *(const float4*)(bb + tid * 4);
  float4 y;
  y.x = av.x + (pa.x + pb.x) * bw.x;
  y.y = av.y + (pa.y + pb.y) * bw.y;
  y.z = av.z + (pa.z + pb.z) * bw.z;
  y.w = av.w + (pa.w + pb.w) * bw.w;
  float s  = y.x + y.y + y.z + y.w;
  float ss = y.x*y.x + y.y*y.y + y.z*y.z + y.w*y.w;
#pragma unroll
  for (int o = 32; o >= 1; o >>= 1) { s += __shfl_xor(s, o); ss += __shfl_xor(ss, o); }
  __shared__ float red[2][4];
  if (lane == 0) { red[0][wave] = s; red[1][wave] = ss; }
  __syncthreads();
  s  = red[0][0] + red[0][1] + red[0][2] + red[0][3];
  ss = red[1][0] + red[1][1] + red[1][2] + red[1][3];
  const float mean = s * (1.0f / (float)H);
  float var = (ss - (float)H * mean * mean) * (1.0f / (float)(H - 1));
  var = fmaxf(var, 0.0f);
  const float inv = 1.0f / (sqrtf(var) + 1e-6f);
  const float4 gv = *(const float4*)(gamma + tid * 4);
  const float4 be = *(const float4*)(beta + tid * 4);
  float4 o;
  o.x = gv.x * (y.x - mean) * inv + be.x;
  o.y = gv.y * (y.y - mean) * inv + be.y;
  o.z = gv.z * (y.z - mean) * inv + be.z;
  o.w = gv.w * (y.w - mean) * inv + be.w;
  *(float4*)(out + off) = o;
}

// ---------------------------------------------------------------------------
extern "C" void kernel_launch(void* const* d_in, const int* in_sizes, int n_in,
                              void* d_out, int out_size, void* d_ws, size_t ws_size,
                              hipStream_t stream)
{
  const float* x    = (const float*)d_in[0];
  const float* Wqkv = (const float*)d_in[1];
  const float* bqkv = (const float*)d_in[2];
  const float* W1   = (const float*)d_in[3];
  const float* b1   = (const float*)d_in[4];
  const float* W2   = (const float*)d_in[5];
  const float* b2   = (const float*)d_in[6];
  const float* g1   = (const float*)d_in[7];
  const float* be1  = (const float*)d_in[8];
  const float* g2   = (const float*)d_in[9];
  const float* be2  = (const float*)d_in[10];
  float* out = (float*)d_out;
  char* w = (char*)d_ws;

  // ---- workspace map (bytes); regions time-multiplexed, peak ~145 MB ----
  float* qkv  = (float*)(w + 0);          // 50.33M  steps 3-4
  u16*   h1b  = (u16*)  (w + 0);          // 33.55M  steps 9-11
  u16*   W1T  = (u16*)  (w + 35651584);   // 8.39M   steps 8-9
  u16*   W2T  = (u16*)  (w + 44040192);   // 8.39M   steps 10-11
  u16*   xh   = (u16*)  (w + 52428800);   // 8.39M   steps 1-3
  u16*   xl   = (u16*)  (w + 60817408);   // 8.39M   steps 1-3
  u16*   Qh   = (u16*)  (w + 52428800);   // 8.39M   steps 4-6 (over xh)
  u16*   Ql   = (u16*)  (w + 60817408);   // 8.39M   steps 4-6 (over xl)
  u16*   WqTh = (u16*)  (w + 69206016);   // 6.29M   steps 2-3
  u16*   WqTl = (u16*)  (w + 75497472);   // 6.29M   steps 2-3
  u16*   Khb  = (u16*)  (w + 69206016);   // 8.39M   steps 4-6 (over WqT*)
  u16*   Klb  = (u16*)  (w + 77594624);   // 8.39M   steps 4-6
  u16*   Vbb  = (u16*)  (w + 85983232);   // 8.39M   steps 4-5
  u16*   VTb  = (u16*)  (w + 94371840);   // 8.39M   steps 5-6
  float* pAB  = (float*)(w + 52428800);   // 33.55M  steps 11-12 (over Q/K dead)
  float* attn = (float*)(w + 102760448);  // 16.78M  steps 6-7
  float* ln1  = (float*)(w + 119537664);  // 16.78M  steps 7-12
  u16*   ln1b = (u16*)  (w + 136314880);  // 8.39M   steps 7-9

  // 1. split x -> bf16 hi/lo
  split_hl<<<4096, 256, 0, stream>>>(x, xh, xl);
  // 2. Wqkv^T hi/lo bf16
  transpose_bf16<1><<<dim3(48, 16), 256, 0, stream>>>(Wqkv, WqTh, WqTl, H, 3*H);
  // 3. qkv = (x @ Wqkv) * bqkv  [split MFMA, 2-phase; V-col Bl staging skipped]
  mfma_gemm<1,0,0,1,0,0><<<24 * 32, 256, 0, stream>>>(xh, xl, WqTh, WqTl, bqkv,
                                                      qkv, nullptr, M_TOK, 3*H, H);
  // 4. repack heads -> scaled/split bf16 Q,K + bf16 V
  repack_qkv<<<M_TOK, 256, 0, stream>>>(qkv, Qh, Ql, Khb, Klb, Vbb);
  // 5. V transpose
  vtrans<<<dim3(T/64, B*NH), 256, 0, stream>>>(Vbb, VTb);
  // 6. attention (MFMA, swapped-operand, XCD-clustered, 8-wave, 3-deep)
  flash_attn_mfma<<<512, 512, 0, stream>>>(Qh, Ql, Khb, Klb, VTb, attn);
  // 7. ln1 = LN(x + attn) (+ bf16 copy)
  ln_residual<<<M_TOK, 256, 0, stream>>>(x, attn, g1, be1, ln1, ln1b);
  // 8. W1^T bf16
  transpose_bf16<0><<<dim3(64, 16), 256, 0, stream>>>(W1, W1T, nullptr, H, FF);
  // 9. h1 = relu((ln1 @ W1) * b1) -> bf16  [XCD-chunked, 3-deep]
  mfma_gemm<0,1,1,0,1,0><<<32 * 32, 256, 0, stream>>>(ln1b, nullptr, W1T, nullptr, b1,
                                                      nullptr, h1b, M_TOK, FF, H);
  // 10. W2^T bf16
  transpose_bf16<0><<<dim3(16, 64), 256, 0, stream>>>(W2, W2T, nullptr, FF, H);
  // 11. ffn partials = h1 @ W2 (split-K=2, raw fp32)  [XCD-chunked, 3-deep]
  mfma_gemm<0,0,0,0,1,1><<<dim3(8 * 32, 2), 256, 0, stream>>>(h1b, nullptr, W2T, nullptr, nullptr,
                                                              pAB, nullptr, M_TOK, H, FF);
  // 12. out = LN(ln1 + (pA+pB)*b2)
  ln_residual_sk<<<M_TOK, 256, 0, stream>>>(ln1, pAB, pAB + 4194304, b2, g2, be2, out);
}